// Round 3
// baseline (1698.094 us; speedup 1.0000x reference)
//
#include <hip/hip_runtime.h>

#define B_ 2
#define S_ 2048
#define HID_ 768
#define NH_ 12
#define HD_ 64
#define NSPLIT 2
#define KSPAN (S_ / NSPLIT)
#define NROWS (B_ * NH_ * S_)   // 49152 total (bh, s) rows

typedef unsigned short u16;
typedef __attribute__((ext_vector_type(8))) short bf16x8;
typedef __attribute__((ext_vector_type(4))) float f32x4;

static __device__ inline u16 f2bf(float f) {
    union { float f; unsigned u; } v; v.f = f;
    unsigned r = v.u + 0x7fffu + ((v.u >> 16) & 1u);
    return (u16)(r >> 16);
}

// LDS-only barrier: waits ds ops, leaves vmcnt (global loads) IN FLIGHT.
#define LDS_BARRIER() asm volatile("s_waitcnt lgkmcnt(0)\n\ts_barrier" ::: "memory")

// ---------------- cast fp32 -> bf16, 4 elems/thread ----------------
__global__ void cast_bf16(const float* __restrict__ src, u16* __restrict__ dst, int n) {
    int i = (blockIdx.x * blockDim.x + threadIdx.x) * 4;
    if (i < n) {
        float4 v = *(const float4*)(src + i);
        unsigned lo = (unsigned)f2bf(v.x) | ((unsigned)f2bf(v.y) << 16);
        unsigned hi = (unsigned)f2bf(v.z) | ((unsigned)f2bf(v.w) << 16);
        uint2 o; o.x = lo; o.y = hi;
        *(uint2*)(dst + i) = o;
    }
}

// ---------------- QKV projection GEMM ----------------
__global__ __launch_bounds__(256) void qkv_gemm(
    const u16* __restrict__ hsb, const u16* __restrict__ wcat,
    const float* __restrict__ bq, const float* __restrict__ bk, const float* __restrict__ bv,
    u16* __restrict__ Qg, u16* __restrict__ Kg, u16* __restrict__ Vtg)
{
    __shared__ u16 As[64 * 40];
    __shared__ u16 Bs[64 * 40];
    __shared__ u16 Vs[64 * 72];

    const int m0 = blockIdx.x * 64;
    const int n0 = blockIdx.y * 64;
    const int tid = threadIdx.x;
    const int wave = tid >> 6, lane = tid & 63;
    const int l = lane & 15, quad = lane >> 4;

    f32x4 acc[4];
#pragma unroll
    for (int t = 0; t < 4; t++) acc[t] = (f32x4){0.f, 0.f, 0.f, 0.f};

    const int srow = tid >> 2;          // 0..63
    const int skg = (tid & 3) * 8;      // 0,8,16,24

    for (int k0 = 0; k0 < HID_; k0 += 32) {
        *(int4*)(&As[srow * 40 + skg]) = *(const int4*)(&hsb[(size_t)(m0 + srow) * HID_ + k0 + skg]);
        *(int4*)(&Bs[srow * 40 + skg]) = *(const int4*)(&wcat[(size_t)(n0 + srow) * HID_ + k0 + skg]);
        __syncthreads();
        bf16x8 a = *(const bf16x8*)(&As[(wave * 16 + l) * 40 + quad * 8]);
#pragma unroll
        for (int t = 0; t < 4; t++) {
            bf16x8 b = *(const bf16x8*)(&Bs[(t * 16 + l) * 40 + quad * 8]);
            acc[t] = __builtin_amdgcn_mfma_f32_16x16x32_bf16(a, b, acc[t], 0, 0, 0);
        }
        __syncthreads();
    }

    const int proj = n0 / HID_;             // 0=Q 1=K 2=V
    const int cbase = n0 - proj * HID_;     // multiple of 64
    const int h = cbase >> 6;
    const int bidx = m0 >> 11;
    const int srow0 = m0 & (S_ - 1);
    const float* bias = (proj == 0) ? bq : ((proj == 1) ? bk : bv);

    if (proj < 2) {
        u16* dst = (proj == 0) ? Qg : Kg;
        const float sc = (proj == 0) ? 0.125f : 1.0f;
#pragma unroll
        for (int t = 0; t < 4; t++) {
            const int d = t * 16 + l;
            const float bb = bias[cbase + d];
#pragma unroll
            for (int rr = 0; rr < 4; rr++) {
                int s = srow0 + wave * 16 + quad * 4 + rr;
                float v = (acc[t][rr] + bb) * sc;
                dst[(((size_t)bidx * NH_ + h) * S_ + s) * HD_ + d] = f2bf(v);
            }
        }
    } else {
        // V: transpose through LDS, write Vt[b][h][d][s] coalesced
#pragma unroll
        for (int t = 0; t < 4; t++) {
            const int d = t * 16 + l;
            const float bb = bias[cbase + d];
#pragma unroll
            for (int rr = 0; rr < 4; rr++) {
                int sl = wave * 16 + quad * 4 + rr;
                Vs[d * 72 + sl] = f2bf(acc[t][rr] + bb);
            }
        }
        __syncthreads();
        const int drow = tid >> 2;           // d 0..63
        const int sseg = (tid & 3) * 16;     // s segment
        size_t base = (((size_t)bidx * NH_ + h) * HD_ + drow) * S_ + srow0 + sseg;
        *(int4*)(&Vtg[base])     = *(const int4*)(&Vs[drow * 72 + sseg]);
        *(int4*)(&Vtg[base + 8]) = *(const int4*)(&Vs[drow * 72 + sseg + 8]);
    }
}

// ---------------- fused flash attention, 2-way split-K ----------------
// grid: (S/64, NH, B*NSPLIT), 256 threads = 4 waves.
// blockIdx.z = b*NSPLIT + split; block processes keys [split*KSPAN, (split+1)*KSPAN).
// Doubles the grid (1536 blocks -> 5 resident blocks/CU, 20 waves/CU) to raise
// memory-level parallelism: each wave keeps ~12 rel/rel2/mask float4 loads plus
// K/V loads in flight; with 67% more waves/CU the outstanding-byte pool grows
// proportionally. Partial (O, m, l) written per split; combine kernel merges.
__global__ __launch_bounds__(256, 5) void attn(
    const u16* __restrict__ Qg, const u16* __restrict__ Kg, const u16* __restrict__ Vtg,
    const float* __restrict__ rel, const float* __restrict__ rel2,
    const int* __restrict__ mask,
    float* __restrict__ Opart, float* __restrict__ Mpart, float* __restrict__ Lpart)
{
    __shared__ u16 Ks[64 * 72];
    __shared__ u16 Vts[64 * 72];
    __shared__ u16 Ps[4 * 16 * 72];

    const int q0 = blockIdx.x * 64;
    const int h = blockIdx.y;
    const int b = blockIdx.z / NSPLIT;
    const int split = blockIdx.z - b * NSPLIT;
    const int tid = threadIdx.x;
    const int wave = tid >> 6, lane = tid & 63;
    const int l = lane & 15, quad = lane >> 4;
    const int bh = b * NH_ + h;
    const int kbase = split * KSPAN;
    const int kend = kbase + KSPAN;

    const float NEG = -3.4028234663852886e38f;

    // Q fragments (B-operand of swapped MFMA) stay in registers
    bf16x8 qf[2];
    {
        const int qr = q0 + wave * 16 + l;
        qf[0] = *(const bf16x8*)(&Qg[((size_t)bh * S_ + qr) * HD_ + quad * 8]);
        qf[1] = *(const bf16x8*)(&Qg[((size_t)bh * S_ + qr) * HD_ + 32 + quad * 8]);
    }

    f32x4 o[4];
#pragma unroll
    for (int t = 0; t < 4; t++) o[t] = (f32x4){0.f, 0.f, 0.f, 0.f};
    float m_run = NEG, l_run = 0.f;   // lane reduces q-row q0+wave*16+l

    const int srow = tid >> 2;        // 0..63
    const int sseg = (tid & 3) * 8;   // 0,8,16,24

    const int qrow = q0 + wave * 16 + l;
    const float* relR  = rel  + (size_t)bh * S_ * S_ + (size_t)qrow * S_;
    const float* rel2R = rel2 + (size_t)bh * S_ * S_ + (size_t)qrow * S_;
    const int*   maskR = mask + (size_t)b * S_ * S_ + (size_t)qrow * S_;

    // prefetch first tile's rel/rel2/mask
    float4 pr1[4], pr2[4];
    int4 pmk[4];
#pragma unroll
    for (int t = 0; t < 4; t++) {
        const int c = kbase + t * 16 + quad * 4;
        pr1[t] = *(const float4*)(relR + c);
        pr2[t] = *(const float4*)(rel2R + c);
        pmk[t] = *(const int4*)(maskR + c);
    }

    for (int k0 = kbase; k0 < kend; k0 += 64) {
        // A: issue K/V staging loads (oldest in vmem queue)
        size_t kg = ((size_t)bh * S_ + k0 + srow) * HD_;
        int4 ka = *(const int4*)(&Kg[kg + sseg]);
        int4 kb = *(const int4*)(&Kg[kg + 32 + sseg]);
        size_t vg = ((size_t)bh * HD_ + srow) * S_ + k0;
        int4 va = *(const int4*)(&Vtg[vg + sseg]);
        int4 vb = *(const int4*)(&Vtg[vg + 32 + sseg]);

        // B: consume prefetched rel/rel2/mask -> score acc init (mask pre-folded:
        // adding |qk|<=1e4 to -3.4e38 is below the ulp -> bit-identical)
        f32x4 sacc[4];
#pragma unroll
        for (int t = 0; t < 4; t++) {
            sacc[t][0] = pmk[t].x ? NEG : pr1[t].x + pr2[t].x;
            sacc[t][1] = pmk[t].y ? NEG : pr1[t].y + pr2[t].y;
            sacc[t][2] = pmk[t].z ? NEG : pr1[t].z + pr2[t].z;
            sacc[t][3] = pmk[t].w ? NEG : pr1[t].w + pr2[t].w;
        }

        // C: prefetch next tile (stays in flight across lgkm-only barriers)
        if (k0 + 64 < kend) {
#pragma unroll
            for (int t = 0; t < 4; t++) {
                const int c = k0 + 64 + t * 16 + quad * 4;
                pr1[t] = *(const float4*)(relR + c);
                pr2[t] = *(const float4*)(rel2R + c);
                pmk[t] = *(const int4*)(maskR + c);
            }
        }

        // D: write staged K/V to LDS (counted vmcnt waits only for ka..vb)
        *(int4*)(&Ks[srow * 72 + sseg])       = ka;
        *(int4*)(&Ks[srow * 72 + 32 + sseg])  = kb;
        *(int4*)(&Vts[srow * 72 + sseg])      = va;
        *(int4*)(&Vts[srow * 72 + 32 + sseg]) = vb;
        LDS_BARRIER();

        // E: swapped QK^T: sacc[t][rr] = scores[qrow][k0 + t*16 + quad*4 + rr]
#pragma unroll
        for (int t = 0; t < 4; t++) {
            bf16x8 b0 = *(const bf16x8*)(&Ks[(t * 16 + l) * 72 + quad * 8]);
            sacc[t] = __builtin_amdgcn_mfma_f32_16x16x32_bf16(b0, qf[0], sacc[t], 0, 0, 0);
            bf16x8 b1 = *(const bf16x8*)(&Ks[(t * 16 + l) * 72 + 32 + quad * 8]);
            sacc[t] = __builtin_amdgcn_mfma_f32_16x16x32_bf16(b1, qf[1], sacc[t], 0, 0, 0);
        }

        // F: online softmax (lanes {l,l+16,l+32,l+48} share a q-row)
        float mx = NEG;
#pragma unroll
        for (int t = 0; t < 4; t++)
#pragma unroll
            for (int rr = 0; rr < 4; rr++) mx = fmaxf(mx, sacc[t][rr]);
        mx = fmaxf(mx, __shfl_xor(mx, 16, 64));
        mx = fmaxf(mx, __shfl_xor(mx, 32, 64));
        float mnew = fmaxf(m_run, mx);
        float alpha = __expf(m_run - mnew);
        float rs = 0.f;
#pragma unroll
        for (int t = 0; t < 4; t++)
#pragma unroll
            for (int rr = 0; rr < 4; rr++) {
                float p = __expf(sacc[t][rr] - mnew);
                sacc[t][rr] = p;
                rs += p;
            }
        rs += __shfl_xor(rs, 16, 64);
        rs += __shfl_xor(rs, 32, 64);
        l_run = l_run * alpha + rs;
        m_run = mnew;

        float av[4];
#pragma unroll
        for (int rr = 0; rr < 4; rr++) av[rr] = __shfl(alpha, quad * 4 + rr, 64);
#pragma unroll
        for (int dt = 0; dt < 4; dt++)
#pragma unroll
            for (int rr = 0; rr < 4; rr++) o[dt][rr] *= av[rr];

        // G: write P to LDS (wave-private rows; same-wave DS ordering suffices)
#pragma unroll
        for (int t = 0; t < 4; t++) {
            unsigned p01 = (unsigned)f2bf(sacc[t][0]) | ((unsigned)f2bf(sacc[t][1]) << 16);
            unsigned p23 = (unsigned)f2bf(sacc[t][2]) | ((unsigned)f2bf(sacc[t][3]) << 16);
            uint2 pw; pw.x = p01; pw.y = p23;
            *(uint2*)(&Ps[(wave * 16 + l) * 72 + t * 16 + quad * 4]) = pw;
        }

        // H: PV: O += P * V
        bf16x8 pa0 = *(const bf16x8*)(&Ps[(wave * 16 + l) * 72 + quad * 8]);
        bf16x8 pa1 = *(const bf16x8*)(&Ps[(wave * 16 + l) * 72 + 32 + quad * 8]);
#pragma unroll
        for (int dt = 0; dt < 4; dt++) {
            bf16x8 v0 = *(const bf16x8*)(&Vts[(dt * 16 + l) * 72 + quad * 8]);
            o[dt] = __builtin_amdgcn_mfma_f32_16x16x32_bf16(pa0, v0, o[dt], 0, 0, 0);
            bf16x8 v1 = *(const bf16x8*)(&Vts[(dt * 16 + l) * 72 + 32 + quad * 8]);
            o[dt] = __builtin_amdgcn_mfma_f32_16x16x32_bf16(pa1, v1, o[dt], 0, 0, 0);
        }
        LDS_BARRIER();
    }

    // epilogue: unnormalized partial O + per-row (m, l) for this split
    float* Op = Opart + (((size_t)split * B_ * NH_ + bh) * S_ + q0) * HD_;
#pragma unroll
    for (int dt = 0; dt < 4; dt++) {
#pragma unroll
        for (int rr = 0; rr < 4; rr++) {
            const int row = wave * 16 + quad * 4 + rr;
            Op[(size_t)row * HD_ + dt * 16 + l] = o[dt][rr];
        }
    }
    if (quad == 0) {
        const size_t mi = ((size_t)split * B_ * NH_ + bh) * S_ + q0 + wave * 16 + l;
        Mpart[mi] = m_run;
        Lpart[mi] = l_run;
    }
}

// ---------------- split-K combine ----------------
// One thread per (row, 4 d-elems). Standard flash merge in f32:
//   m = max(m0,m1); out = (O0*e^{m0-m} + O1*e^{m1-m}) / (l0*e^{m0-m} + l1*e^{m1-m})
__global__ __launch_bounds__(256) void combine(
    const float* __restrict__ Op, const float* __restrict__ Mp, const float* __restrict__ Lp,
    float* __restrict__ out)
{
    const int idx = blockIdx.x * 256 + threadIdx.x;   // NROWS*16 total
    const int r = idx >> 4;            // bh*S + s
    const int dseg = (idx & 15) * 4;
    const float m0 = Mp[r], m1 = Mp[NROWS + r];
    const float l0 = Lp[r], l1 = Lp[NROWS + r];
    const float m = fmaxf(m0, m1);
    const float a0 = __expf(m0 - m), a1 = __expf(m1 - m);
    const float inv = 1.0f / (l0 * a0 + l1 * a1);
    const float4 o0 = *(const float4*)(Op + (size_t)r * HD_ + dseg);
    const float4 o1 = *(const float4*)(Op + ((size_t)NROWS + r) * HD_ + dseg);
    float4 res;
    res.x = (o0.x * a0 + o1.x * a1) * inv;
    res.y = (o0.y * a0 + o1.y * a1) * inv;
    res.z = (o0.z * a0 + o1.z * a1) * inv;
    res.w = (o0.w * a0 + o1.w * a1) * inv;
    const int bh_ = r >> 11;                // r / S_
    const int s = r & (S_ - 1);
    const int b = bh_ / NH_;
    const int h = bh_ - b * NH_;
    *(float4*)(out + ((size_t)(b * S_ + s)) * HID_ + h * HD_ + dseg) = res;
}

extern "C" void kernel_launch(void* const* d_in, const int* in_sizes, int n_in,
                              void* d_out, int out_size, void* d_ws, size_t ws_size,
                              hipStream_t stream) {
    const float* hs   = (const float*)d_in[0];
    const float* rel  = (const float*)d_in[1];
    const float* rel2 = (const float*)d_in[2];
    const int*   mask = (const int*)d_in[3];
    const float* Wq = (const float*)d_in[4];
    const float* bq = (const float*)d_in[5];
    const float* Wk = (const float*)d_in[6];
    const float* bk = (const float*)d_in[7];
    const float* Wv = (const float*)d_in[8];
    const float* bv = (const float*)d_in[9];
    float* out = (float*)d_out;

    char* ws = (char*)d_ws;
    u16* hsb   = (u16*)(ws);                      // 4096*768 bf16   = 6291456 B
    u16* wcat  = (u16*)(ws + 6291456);            // 2304*768 bf16   = 3538944 B
    u16* Qg    = (u16*)(ws + 9830400);            // [B][NH][S][HD]  = 6291456 B
    u16* Kg    = (u16*)(ws + 16121856);           // same
    u16* Vtg   = (u16*)(ws + 22413312);           // [B][NH][HD][S]  = 6291456 B
    float* Opart = (float*)(ws + 28704768);       // [2][B][NH][S][HD] f32 = 25165824 B
    float* Mpart = (float*)(ws + 53870592);       // [2][B*NH*S] f32 = 393216 B
    float* Lpart = (float*)(ws + 54263808);       // [2][B*NH*S] f32 = 393216 B

    // casts
    cast_bf16<<<3072, 256, 0, stream>>>(hs, hsb, B_ * S_ * HID_);
    cast_bf16<<<576, 256, 0, stream>>>(Wq, wcat,             HID_ * HID_);
    cast_bf16<<<576, 256, 0, stream>>>(Wk, wcat + HID_ * HID_,     HID_ * HID_);
    cast_bf16<<<576, 256, 0, stream>>>(Wv, wcat + 2 * HID_ * HID_, HID_ * HID_);

    // QKV projections
    qkv_gemm<<<dim3(64, 36), 256, 0, stream>>>(hsb, wcat, bq, bk, bv, Qg, Kg, Vtg);

    // fused attention, 2-way split-K
    attn<<<dim3(S_ / 64, NH_, B_ * NSPLIT), 256, 0, stream>>>(
        Qg, Kg, Vtg, rel, rel2, mask, Opart, Mpart, Lpart);

    // merge halves
    combine<<<(NROWS * 16) / 256, 256, 0, stream>>>(Opart, Mpart, Lpart, out);
}

// Round 4
// 1102.175 us; speedup vs baseline: 1.5407x; 1.5407x over previous
//
#include <hip/hip_runtime.h>

#define B_ 2
#define S_ 2048
#define HID_ 768
#define NH_ 12
#define HD_ 64
#define NSPLIT 2
#define KSPAN (S_ / NSPLIT)
#define NROWS (B_ * NH_ * S_)   // 49152 total (bh, s) rows

typedef unsigned short u16;
typedef __attribute__((ext_vector_type(8))) short bf16x8;
typedef __attribute__((ext_vector_type(4))) float f32x4;

static __device__ inline u16 f2bf(float f) {
    union { float f; unsigned u; } v; v.f = f;
    unsigned r = v.u + 0x7fffu + ((v.u >> 16) & 1u);
    return (u16)(r >> 16);
}

// LDS-only barrier: waits ds ops, leaves vmcnt (global loads) IN FLIGHT.
#define LDS_BARRIER() asm volatile("s_waitcnt lgkmcnt(0)\n\ts_barrier" ::: "memory")

// ---------------- cast fp32 -> bf16, 4 elems/thread ----------------
__global__ void cast_bf16(const float* __restrict__ src, u16* __restrict__ dst, int n) {
    int i = (blockIdx.x * blockDim.x + threadIdx.x) * 4;
    if (i < n) {
        float4 v = *(const float4*)(src + i);
        unsigned lo = (unsigned)f2bf(v.x) | ((unsigned)f2bf(v.y) << 16);
        unsigned hi = (unsigned)f2bf(v.z) | ((unsigned)f2bf(v.w) << 16);
        uint2 o; o.x = lo; o.y = hi;
        *(uint2*)(dst + i) = o;
    }
}

// ---------------- QKV projection GEMM ----------------
__global__ __launch_bounds__(256) void qkv_gemm(
    const u16* __restrict__ hsb, const u16* __restrict__ wcat,
    const float* __restrict__ bq, const float* __restrict__ bk, const float* __restrict__ bv,
    u16* __restrict__ Qg, u16* __restrict__ Kg, u16* __restrict__ Vtg)
{
    __shared__ u16 As[64 * 40];
    __shared__ u16 Bs[64 * 40];
    __shared__ u16 Vs[64 * 72];

    const int m0 = blockIdx.x * 64;
    const int n0 = blockIdx.y * 64;
    const int tid = threadIdx.x;
    const int wave = tid >> 6, lane = tid & 63;
    const int l = lane & 15, quad = lane >> 4;

    f32x4 acc[4];
#pragma unroll
    for (int t = 0; t < 4; t++) acc[t] = (f32x4){0.f, 0.f, 0.f, 0.f};

    const int srow = tid >> 2;          // 0..63
    const int skg = (tid & 3) * 8;      // 0,8,16,24

    for (int k0 = 0; k0 < HID_; k0 += 32) {
        *(int4*)(&As[srow * 40 + skg]) = *(const int4*)(&hsb[(size_t)(m0 + srow) * HID_ + k0 + skg]);
        *(int4*)(&Bs[srow * 40 + skg]) = *(const int4*)(&wcat[(size_t)(n0 + srow) * HID_ + k0 + skg]);
        __syncthreads();
        bf16x8 a = *(const bf16x8*)(&As[(wave * 16 + l) * 40 + quad * 8]);
#pragma unroll
        for (int t = 0; t < 4; t++) {
            bf16x8 b = *(const bf16x8*)(&Bs[(t * 16 + l) * 40 + quad * 8]);
            acc[t] = __builtin_amdgcn_mfma_f32_16x16x32_bf16(a, b, acc[t], 0, 0, 0);
        }
        __syncthreads();
    }

    const int proj = n0 / HID_;             // 0=Q 1=K 2=V
    const int cbase = n0 - proj * HID_;     // multiple of 64
    const int h = cbase >> 6;
    const int bidx = m0 >> 11;
    const int srow0 = m0 & (S_ - 1);
    const float* bias = (proj == 0) ? bq : ((proj == 1) ? bk : bv);

    if (proj < 2) {
        u16* dst = (proj == 0) ? Qg : Kg;
        const float sc = (proj == 0) ? 0.125f : 1.0f;
#pragma unroll
        for (int t = 0; t < 4; t++) {
            const int d = t * 16 + l;
            const float bb = bias[cbase + d];
#pragma unroll
            for (int rr = 0; rr < 4; rr++) {
                int s = srow0 + wave * 16 + quad * 4 + rr;
                float v = (acc[t][rr] + bb) * sc;
                dst[(((size_t)bidx * NH_ + h) * S_ + s) * HD_ + d] = f2bf(v);
            }
        }
    } else {
        // V: transpose through LDS, write Vt[b][h][d][s] coalesced
#pragma unroll
        for (int t = 0; t < 4; t++) {
            const int d = t * 16 + l;
            const float bb = bias[cbase + d];
#pragma unroll
            for (int rr = 0; rr < 4; rr++) {
                int sl = wave * 16 + quad * 4 + rr;
                Vs[d * 72 + sl] = f2bf(acc[t][rr] + bb);
            }
        }
        __syncthreads();
        const int drow = tid >> 2;           // d 0..63
        const int sseg = (tid & 3) * 16;     // s segment
        size_t base = (((size_t)bidx * NH_ + h) * HD_ + drow) * S_ + srow0 + sseg;
        *(int4*)(&Vtg[base])     = *(const int4*)(&Vs[drow * 72 + sseg]);
        *(int4*)(&Vtg[base + 8]) = *(const int4*)(&Vs[drow * 72 + sseg + 8]);
    }
}

// ---------------- fused flash attention, 2-way split-K ----------------
// grid: (S/64, NH, B*NSPLIT), 256 threads = 4 waves.
// __launch_bounds__(256, 4): 4 waves/EU = 4 blocks/CU (16 waves/CU), VGPR cap
// 128 >= the ~92 this kernel needs -> NO spill (round 3's (256,5) capped at 48
// VGPR and spilled 4 GB of scratch). LDS 4x27.6KB = 110KB <= 160KB. Round 3
// proved the memory system serves ~3.7 TB/s at this concurrency.
__global__ __launch_bounds__(256, 4) void attn(
    const u16* __restrict__ Qg, const u16* __restrict__ Kg, const u16* __restrict__ Vtg,
    const float* __restrict__ rel, const float* __restrict__ rel2,
    const int* __restrict__ mask,
    float* __restrict__ Opart, float* __restrict__ Mpart, float* __restrict__ Lpart)
{
    __shared__ u16 Ks[64 * 72];
    __shared__ u16 Vts[64 * 72];
    __shared__ u16 Ps[4 * 16 * 72];

    const int q0 = blockIdx.x * 64;
    const int h = blockIdx.y;
    const int b = blockIdx.z / NSPLIT;
    const int split = blockIdx.z - b * NSPLIT;
    const int tid = threadIdx.x;
    const int wave = tid >> 6, lane = tid & 63;
    const int l = lane & 15, quad = lane >> 4;
    const int bh = b * NH_ + h;
    const int kbase = split * KSPAN;
    const int kend = kbase + KSPAN;

    const float NEG = -3.4028234663852886e38f;

    // Q fragments (B-operand of swapped MFMA) stay in registers
    bf16x8 qf[2];
    {
        const int qr = q0 + wave * 16 + l;
        qf[0] = *(const bf16x8*)(&Qg[((size_t)bh * S_ + qr) * HD_ + quad * 8]);
        qf[1] = *(const bf16x8*)(&Qg[((size_t)bh * S_ + qr) * HD_ + 32 + quad * 8]);
    }

    f32x4 o[4];
#pragma unroll
    for (int t = 0; t < 4; t++) o[t] = (f32x4){0.f, 0.f, 0.f, 0.f};
    float m_run = NEG, l_run = 0.f;   // lane reduces q-row q0+wave*16+l

    const int srow = tid >> 2;        // 0..63
    const int sseg = (tid & 3) * 8;   // 0,8,16,24

    const int qrow = q0 + wave * 16 + l;
    const float* relR  = rel  + (size_t)bh * S_ * S_ + (size_t)qrow * S_;
    const float* rel2R = rel2 + (size_t)bh * S_ * S_ + (size_t)qrow * S_;
    const int*   maskR = mask + (size_t)b * S_ * S_ + (size_t)qrow * S_;

    // prefetch first tile's rel/rel2/mask
    float4 pr1[4], pr2[4];
    int4 pmk[4];
#pragma unroll
    for (int t = 0; t < 4; t++) {
        const int c = kbase + t * 16 + quad * 4;
        pr1[t] = *(const float4*)(relR + c);
        pr2[t] = *(const float4*)(rel2R + c);
        pmk[t] = *(const int4*)(maskR + c);
    }

    for (int k0 = kbase; k0 < kend; k0 += 64) {
        // A: issue K/V staging loads (oldest in vmem queue)
        size_t kg = ((size_t)bh * S_ + k0 + srow) * HD_;
        int4 ka = *(const int4*)(&Kg[kg + sseg]);
        int4 kb = *(const int4*)(&Kg[kg + 32 + sseg]);
        size_t vg = ((size_t)bh * HD_ + srow) * S_ + k0;
        int4 va = *(const int4*)(&Vtg[vg + sseg]);
        int4 vb = *(const int4*)(&Vtg[vg + 32 + sseg]);

        // B: consume prefetched rel/rel2/mask -> score acc init (mask pre-folded:
        // adding |qk|<=1e4 to -3.4e38 is below the ulp -> bit-identical)
        f32x4 sacc[4];
#pragma unroll
        for (int t = 0; t < 4; t++) {
            sacc[t][0] = pmk[t].x ? NEG : pr1[t].x + pr2[t].x;
            sacc[t][1] = pmk[t].y ? NEG : pr1[t].y + pr2[t].y;
            sacc[t][2] = pmk[t].z ? NEG : pr1[t].z + pr2[t].z;
            sacc[t][3] = pmk[t].w ? NEG : pr1[t].w + pr2[t].w;
        }

        // C: prefetch next tile (stays in flight across lgkm-only barriers)
        if (k0 + 64 < kend) {
#pragma unroll
            for (int t = 0; t < 4; t++) {
                const int c = k0 + 64 + t * 16 + quad * 4;
                pr1[t] = *(const float4*)(relR + c);
                pr2[t] = *(const float4*)(rel2R + c);
                pmk[t] = *(const int4*)(maskR + c);
            }
        }

        // D: write staged K/V to LDS (counted vmcnt waits only for ka..vb)
        *(int4*)(&Ks[srow * 72 + sseg])       = ka;
        *(int4*)(&Ks[srow * 72 + 32 + sseg])  = kb;
        *(int4*)(&Vts[srow * 72 + sseg])      = va;
        *(int4*)(&Vts[srow * 72 + 32 + sseg]) = vb;
        LDS_BARRIER();

        // E: swapped QK^T: sacc[t][rr] = scores[qrow][k0 + t*16 + quad*4 + rr]
#pragma unroll
        for (int t = 0; t < 4; t++) {
            bf16x8 b0 = *(const bf16x8*)(&Ks[(t * 16 + l) * 72 + quad * 8]);
            sacc[t] = __builtin_amdgcn_mfma_f32_16x16x32_bf16(b0, qf[0], sacc[t], 0, 0, 0);
            bf16x8 b1 = *(const bf16x8*)(&Ks[(t * 16 + l) * 72 + 32 + quad * 8]);
            sacc[t] = __builtin_amdgcn_mfma_f32_16x16x32_bf16(b1, qf[1], sacc[t], 0, 0, 0);
        }

        // F: online softmax (lanes {l,l+16,l+32,l+48} share a q-row)
        float mx = NEG;
#pragma unroll
        for (int t = 0; t < 4; t++)
#pragma unroll
            for (int rr = 0; rr < 4; rr++) mx = fmaxf(mx, sacc[t][rr]);
        mx = fmaxf(mx, __shfl_xor(mx, 16, 64));
        mx = fmaxf(mx, __shfl_xor(mx, 32, 64));
        float mnew = fmaxf(m_run, mx);
        float alpha = __expf(m_run - mnew);
        float rs = 0.f;
#pragma unroll
        for (int t = 0; t < 4; t++)
#pragma unroll
            for (int rr = 0; rr < 4; rr++) {
                float p = __expf(sacc[t][rr] - mnew);
                sacc[t][rr] = p;
                rs += p;
            }
        rs += __shfl_xor(rs, 16, 64);
        rs += __shfl_xor(rs, 32, 64);
        l_run = l_run * alpha + rs;
        m_run = mnew;

        float av[4];
#pragma unroll
        for (int rr = 0; rr < 4; rr++) av[rr] = __shfl(alpha, quad * 4 + rr, 64);
#pragma unroll
        for (int dt = 0; dt < 4; dt++)
#pragma unroll
            for (int rr = 0; rr < 4; rr++) o[dt][rr] *= av[rr];

        // G: write P to LDS (wave-private rows; same-wave DS ordering suffices)
#pragma unroll
        for (int t = 0; t < 4; t++) {
            unsigned p01 = (unsigned)f2bf(sacc[t][0]) | ((unsigned)f2bf(sacc[t][1]) << 16);
            unsigned p23 = (unsigned)f2bf(sacc[t][2]) | ((unsigned)f2bf(sacc[t][3]) << 16);
            uint2 pw; pw.x = p01; pw.y = p23;
            *(uint2*)(&Ps[(wave * 16 + l) * 72 + t * 16 + quad * 4]) = pw;
        }

        // H: PV: O += P * V
        bf16x8 pa0 = *(const bf16x8*)(&Ps[(wave * 16 + l) * 72 + quad * 8]);
        bf16x8 pa1 = *(const bf16x8*)(&Ps[(wave * 16 + l) * 72 + 32 + quad * 8]);
#pragma unroll
        for (int dt = 0; dt < 4; dt++) {
            bf16x8 v0 = *(const bf16x8*)(&Vts[(dt * 16 + l) * 72 + quad * 8]);
            o[dt] = __builtin_amdgcn_mfma_f32_16x16x32_bf16(pa0, v0, o[dt], 0, 0, 0);
            bf16x8 v1 = *(const bf16x8*)(&Vts[(dt * 16 + l) * 72 + 32 + quad * 8]);
            o[dt] = __builtin_amdgcn_mfma_f32_16x16x32_bf16(pa1, v1, o[dt], 0, 0, 0);
        }
        LDS_BARRIER();
    }

    // epilogue: unnormalized partial O + per-row (m, l) for this split
    float* Op = Opart + (((size_t)split * B_ * NH_ + bh) * S_ + q0) * HD_;
#pragma unroll
    for (int dt = 0; dt < 4; dt++) {
#pragma unroll
        for (int rr = 0; rr < 4; rr++) {
            const int row = wave * 16 + quad * 4 + rr;
            Op[(size_t)row * HD_ + dt * 16 + l] = o[dt][rr];
        }
    }
    if (quad == 0) {
        const size_t mi = ((size_t)split * B_ * NH_ + bh) * S_ + q0 + wave * 16 + l;
        Mpart[mi] = m_run;
        Lpart[mi] = l_run;
    }
}

// ---------------- split-K combine ----------------
// One thread per (row, 4 d-elems). Standard flash merge in f32:
//   m = max(m0,m1); out = (O0*e^{m0-m} + O1*e^{m1-m}) / (l0*e^{m0-m} + l1*e^{m1-m})
__global__ __launch_bounds__(256) void combine(
    const float* __restrict__ Op, const float* __restrict__ Mp, const float* __restrict__ Lp,
    float* __restrict__ out)
{
    const int idx = blockIdx.x * 256 + threadIdx.x;   // NROWS*16 total
    const int r = idx >> 4;            // bh*S + s
    const int dseg = (idx & 15) * 4;
    const float m0 = Mp[r], m1 = Mp[NROWS + r];
    const float l0 = Lp[r], l1 = Lp[NROWS + r];
    const float m = fmaxf(m0, m1);
    const float a0 = __expf(m0 - m), a1 = __expf(m1 - m);
    const float inv = 1.0f / (l0 * a0 + l1 * a1);
    const float4 o0 = *(const float4*)(Op + (size_t)r * HD_ + dseg);
    const float4 o1 = *(const float4*)(Op + ((size_t)NROWS + r) * HD_ + dseg);
    float4 res;
    res.x = (o0.x * a0 + o1.x * a1) * inv;
    res.y = (o0.y * a0 + o1.y * a1) * inv;
    res.z = (o0.z * a0 + o1.z * a1) * inv;
    res.w = (o0.w * a0 + o1.w * a1) * inv;
    const int bh_ = r >> 11;                // r / S_
    const int s = r & (S_ - 1);
    const int b = bh_ / NH_;
    const int h = bh_ - b * NH_;
    *(float4*)(out + ((size_t)(b * S_ + s)) * HID_ + h * HD_ + dseg) = res;
}

extern "C" void kernel_launch(void* const* d_in, const int* in_sizes, int n_in,
                              void* d_out, int out_size, void* d_ws, size_t ws_size,
                              hipStream_t stream) {
    const float* hs   = (const float*)d_in[0];
    const float* rel  = (const float*)d_in[1];
    const float* rel2 = (const float*)d_in[2];
    const int*   mask = (const int*)d_in[3];
    const float* Wq = (const float*)d_in[4];
    const float* bq = (const float*)d_in[5];
    const float* Wk = (const float*)d_in[6];
    const float* bk = (const float*)d_in[7];
    const float* Wv = (const float*)d_in[8];
    const float* bv = (const float*)d_in[9];
    float* out = (float*)d_out;

    char* ws = (char*)d_ws;
    u16* hsb   = (u16*)(ws);                      // 4096*768 bf16   = 6291456 B
    u16* wcat  = (u16*)(ws + 6291456);            // 2304*768 bf16   = 3538944 B
    u16* Qg    = (u16*)(ws + 9830400);            // [B][NH][S][HD]  = 6291456 B
    u16* Kg    = (u16*)(ws + 16121856);           // same
    u16* Vtg   = (u16*)(ws + 22413312);           // [B][NH][HD][S]  = 6291456 B
    float* Opart = (float*)(ws + 28704768);       // [2][B][NH][S][HD] f32 = 25165824 B
    float* Mpart = (float*)(ws + 53870592);       // [2][B*NH*S] f32 = 393216 B
    float* Lpart = (float*)(ws + 54263808);       // [2][B*NH*S] f32 = 393216 B

    // casts
    cast_bf16<<<3072, 256, 0, stream>>>(hs, hsb, B_ * S_ * HID_);
    cast_bf16<<<576, 256, 0, stream>>>(Wq, wcat,             HID_ * HID_);
    cast_bf16<<<576, 256, 0, stream>>>(Wk, wcat + HID_ * HID_,     HID_ * HID_);
    cast_bf16<<<576, 256, 0, stream>>>(Wv, wcat + 2 * HID_ * HID_, HID_ * HID_);

    // QKV projections
    qkv_gemm<<<dim3(64, 36), 256, 0, stream>>>(hsb, wcat, bq, bk, bv, Qg, Kg, Vtg);

    // fused attention, 2-way split-K
    attn<<<dim3(S_ / 64, NH_, B_ * NSPLIT), 256, 0, stream>>>(
        Qg, Kg, Vtg, rel, rel2, mask, Opart, Mpart, Lpart);

    // merge halves
    combine<<<(NROWS * 16) / 256, 256, 0, stream>>>(Opart, Mpart, Lpart, out);
}

// Round 5
// 905.687 us; speedup vs baseline: 1.8749x; 1.2169x over previous
//
#include <hip/hip_runtime.h>

#define B_ 2
#define S_ 2048
#define HID_ 768
#define NH_ 12
#define HD_ 64
#define NSPLIT 2
#define KSPAN (S_ / NSPLIT)
#define NROWS (B_ * NH_ * S_)   // 49152 total (bh, s) rows

typedef unsigned short u16;
typedef __attribute__((ext_vector_type(8))) short bf16x8;
typedef __attribute__((ext_vector_type(4))) float f32x4;

static __device__ inline u16 f2bf(float f) {
    union { float f; unsigned u; } v; v.f = f;
    unsigned r = v.u + 0x7fffu + ((v.u >> 16) & 1u);
    return (u16)(r >> 16);
}

// LDS-only barrier: waits ds ops, leaves vmcnt (global loads) IN FLIGHT.
#define LDS_BARRIER() asm volatile("s_waitcnt lgkmcnt(0)\n\ts_barrier" ::: "memory")

// ---------------- cast fp32 -> bf16, 4 elems/thread ----------------
__global__ void cast_bf16(const float* __restrict__ src, u16* __restrict__ dst, int n) {
    int i = (blockIdx.x * blockDim.x + threadIdx.x) * 4;
    if (i < n) {
        float4 v = *(const float4*)(src + i);
        unsigned lo = (unsigned)f2bf(v.x) | ((unsigned)f2bf(v.y) << 16);
        unsigned hi = (unsigned)f2bf(v.z) | ((unsigned)f2bf(v.w) << 16);
        uint2 o; o.x = lo; o.y = hi;
        *(uint2*)(dst + i) = o;
    }
}

// ---------------- QKV projection GEMM ----------------
__global__ __launch_bounds__(256) void qkv_gemm(
    const u16* __restrict__ hsb, const u16* __restrict__ wcat,
    const float* __restrict__ bq, const float* __restrict__ bk, const float* __restrict__ bv,
    u16* __restrict__ Qg, u16* __restrict__ Kg, u16* __restrict__ Vtg)
{
    __shared__ u16 As[64 * 40];
    __shared__ u16 Bs[64 * 40];
    __shared__ u16 Vs[64 * 72];

    const int m0 = blockIdx.x * 64;
    const int n0 = blockIdx.y * 64;
    const int tid = threadIdx.x;
    const int wave = tid >> 6, lane = tid & 63;
    const int l = lane & 15, quad = lane >> 4;

    f32x4 acc[4];
#pragma unroll
    for (int t = 0; t < 4; t++) acc[t] = (f32x4){0.f, 0.f, 0.f, 0.f};

    const int srow = tid >> 2;          // 0..63
    const int skg = (tid & 3) * 8;      // 0,8,16,24

    for (int k0 = 0; k0 < HID_; k0 += 32) {
        *(int4*)(&As[srow * 40 + skg]) = *(const int4*)(&hsb[(size_t)(m0 + srow) * HID_ + k0 + skg]);
        *(int4*)(&Bs[srow * 40 + skg]) = *(const int4*)(&wcat[(size_t)(n0 + srow) * HID_ + k0 + skg]);
        __syncthreads();
        bf16x8 a = *(const bf16x8*)(&As[(wave * 16 + l) * 40 + quad * 8]);
#pragma unroll
        for (int t = 0; t < 4; t++) {
            bf16x8 b = *(const bf16x8*)(&Bs[(t * 16 + l) * 40 + quad * 8]);
            acc[t] = __builtin_amdgcn_mfma_f32_16x16x32_bf16(a, b, acc[t], 0, 0, 0);
        }
        __syncthreads();
    }

    const int proj = n0 / HID_;             // 0=Q 1=K 2=V
    const int cbase = n0 - proj * HID_;     // multiple of 64
    const int h = cbase >> 6;
    const int bidx = m0 >> 11;
    const int srow0 = m0 & (S_ - 1);
    const float* bias = (proj == 0) ? bq : ((proj == 1) ? bk : bv);

    if (proj < 2) {
        u16* dst = (proj == 0) ? Qg : Kg;
        const float sc = (proj == 0) ? 0.125f : 1.0f;
#pragma unroll
        for (int t = 0; t < 4; t++) {
            const int d = t * 16 + l;
            const float bb = bias[cbase + d];
#pragma unroll
            for (int rr = 0; rr < 4; rr++) {
                int s = srow0 + wave * 16 + quad * 4 + rr;
                float v = (acc[t][rr] + bb) * sc;
                dst[(((size_t)bidx * NH_ + h) * S_ + s) * HD_ + d] = f2bf(v);
            }
        }
    } else {
        // V: transpose through LDS, write Vt[b][h][d][s] coalesced
#pragma unroll
        for (int t = 0; t < 4; t++) {
            const int d = t * 16 + l;
            const float bb = bias[cbase + d];
#pragma unroll
            for (int rr = 0; rr < 4; rr++) {
                int sl = wave * 16 + quad * 4 + rr;
                Vs[d * 72 + sl] = f2bf(acc[t][rr] + bb);
            }
        }
        __syncthreads();
        const int drow = tid >> 2;           // d 0..63
        const int sseg = (tid & 3) * 16;     // s segment
        size_t base = (((size_t)bidx * NH_ + h) * HD_ + drow) * S_ + srow0 + sseg;
        *(int4*)(&Vtg[base])     = *(const int4*)(&Vs[drow * 72 + sseg]);
        *(int4*)(&Vtg[base + 8]) = *(const int4*)(&Vs[drow * 72 + sseg + 8]);
    }
}

// ---------------- fused flash attention, 2-way split-K ----------------
// grid: (S/64, NH, B*NSPLIT), 256 threads = 4 waves.
// NO min-waves launch-bound: on gfx950 the 2nd arg splits the unified VGPR/AGPR
// file and caps arch-VGPRs below the ~92 this body needs -> scratch spills
// (round 3: cap 48, 4 GB scratch; round 4: cap 64, 0.9 GB scratch). Plain
// allocation gives ~92 VGPR (round 2, zero spill) <= 128 -> 4 waves/SIMD, and
// the split-K grid (1536 blocks) keeps 4 blocks/CU resident (LDS 110/160 KB),
// the concurrency at which rounds 3/4 sustained 3.0-3.75 TB/s.
__global__ __launch_bounds__(256) void attn(
    const u16* __restrict__ Qg, const u16* __restrict__ Kg, const u16* __restrict__ Vtg,
    const float* __restrict__ rel, const float* __restrict__ rel2,
    const int* __restrict__ mask,
    float* __restrict__ Opart, float* __restrict__ Mpart, float* __restrict__ Lpart)
{
    __shared__ u16 Ks[64 * 72];
    __shared__ u16 Vts[64 * 72];
    __shared__ u16 Ps[4 * 16 * 72];

    const int q0 = blockIdx.x * 64;
    const int h = blockIdx.y;
    const int b = blockIdx.z / NSPLIT;
    const int split = blockIdx.z - b * NSPLIT;
    const int tid = threadIdx.x;
    const int wave = tid >> 6, lane = tid & 63;
    const int l = lane & 15, quad = lane >> 4;
    const int bh = b * NH_ + h;
    const int kbase = split * KSPAN;
    const int kend = kbase + KSPAN;

    const float NEG = -3.4028234663852886e38f;

    // Q fragments (B-operand of swapped MFMA) stay in registers
    bf16x8 qf[2];
    {
        const int qr = q0 + wave * 16 + l;
        qf[0] = *(const bf16x8*)(&Qg[((size_t)bh * S_ + qr) * HD_ + quad * 8]);
        qf[1] = *(const bf16x8*)(&Qg[((size_t)bh * S_ + qr) * HD_ + 32 + quad * 8]);
    }

    f32x4 o[4];
#pragma unroll
    for (int t = 0; t < 4; t++) o[t] = (f32x4){0.f, 0.f, 0.f, 0.f};
    float m_run = NEG, l_run = 0.f;   // lane reduces q-row q0+wave*16+l

    const int srow = tid >> 2;        // 0..63
    const int sseg = (tid & 3) * 8;   // 0,8,16,24

    const int qrow = q0 + wave * 16 + l;
    const float* relR  = rel  + (size_t)bh * S_ * S_ + (size_t)qrow * S_;
    const float* rel2R = rel2 + (size_t)bh * S_ * S_ + (size_t)qrow * S_;
    const int*   maskR = mask + (size_t)b * S_ * S_ + (size_t)qrow * S_;

    // prefetch first tile's rel/rel2/mask
    float4 pr1[4], pr2[4];
    int4 pmk[4];
#pragma unroll
    for (int t = 0; t < 4; t++) {
        const int c = kbase + t * 16 + quad * 4;
        pr1[t] = *(const float4*)(relR + c);
        pr2[t] = *(const float4*)(rel2R + c);
        pmk[t] = *(const int4*)(maskR + c);
    }

    for (int k0 = kbase; k0 < kend; k0 += 64) {
        // A: issue K/V staging loads (oldest in vmem queue)
        size_t kg = ((size_t)bh * S_ + k0 + srow) * HD_;
        int4 ka = *(const int4*)(&Kg[kg + sseg]);
        int4 kb = *(const int4*)(&Kg[kg + 32 + sseg]);
        size_t vg = ((size_t)bh * HD_ + srow) * S_ + k0;
        int4 va = *(const int4*)(&Vtg[vg + sseg]);
        int4 vb = *(const int4*)(&Vtg[vg + 32 + sseg]);

        // B: consume prefetched rel/rel2/mask -> score acc init (mask pre-folded:
        // adding |qk|<=1e4 to -3.4e38 is below the ulp -> bit-identical)
        f32x4 sacc[4];
#pragma unroll
        for (int t = 0; t < 4; t++) {
            sacc[t][0] = pmk[t].x ? NEG : pr1[t].x + pr2[t].x;
            sacc[t][1] = pmk[t].y ? NEG : pr1[t].y + pr2[t].y;
            sacc[t][2] = pmk[t].z ? NEG : pr1[t].z + pr2[t].z;
            sacc[t][3] = pmk[t].w ? NEG : pr1[t].w + pr2[t].w;
        }

        // C: prefetch next tile (stays in flight across lgkm-only barriers)
        if (k0 + 64 < kend) {
#pragma unroll
            for (int t = 0; t < 4; t++) {
                const int c = k0 + 64 + t * 16 + quad * 4;
                pr1[t] = *(const float4*)(relR + c);
                pr2[t] = *(const float4*)(rel2R + c);
                pmk[t] = *(const int4*)(maskR + c);
            }
        }

        // D: write staged K/V to LDS (counted vmcnt waits only for ka..vb)
        *(int4*)(&Ks[srow * 72 + sseg])       = ka;
        *(int4*)(&Ks[srow * 72 + 32 + sseg])  = kb;
        *(int4*)(&Vts[srow * 72 + sseg])      = va;
        *(int4*)(&Vts[srow * 72 + 32 + sseg]) = vb;
        LDS_BARRIER();

        // E: swapped QK^T: sacc[t][rr] = scores[qrow][k0 + t*16 + quad*4 + rr]
#pragma unroll
        for (int t = 0; t < 4; t++) {
            bf16x8 b0 = *(const bf16x8*)(&Ks[(t * 16 + l) * 72 + quad * 8]);
            sacc[t] = __builtin_amdgcn_mfma_f32_16x16x32_bf16(b0, qf[0], sacc[t], 0, 0, 0);
            bf16x8 b1 = *(const bf16x8*)(&Ks[(t * 16 + l) * 72 + 32 + quad * 8]);
            sacc[t] = __builtin_amdgcn_mfma_f32_16x16x32_bf16(b1, qf[1], sacc[t], 0, 0, 0);
        }

        // F: online softmax (lanes {l,l+16,l+32,l+48} share a q-row)
        float mx = NEG;
#pragma unroll
        for (int t = 0; t < 4; t++)
#pragma unroll
            for (int rr = 0; rr < 4; rr++) mx = fmaxf(mx, sacc[t][rr]);
        mx = fmaxf(mx, __shfl_xor(mx, 16, 64));
        mx = fmaxf(mx, __shfl_xor(mx, 32, 64));
        float mnew = fmaxf(m_run, mx);
        float alpha = __expf(m_run - mnew);
        float rs = 0.f;
#pragma unroll
        for (int t = 0; t < 4; t++)
#pragma unroll
            for (int rr = 0; rr < 4; rr++) {
                float p = __expf(sacc[t][rr] - mnew);
                sacc[t][rr] = p;
                rs += p;
            }
        rs += __shfl_xor(rs, 16, 64);
        rs += __shfl_xor(rs, 32, 64);
        l_run = l_run * alpha + rs;
        m_run = mnew;

        float av[4];
#pragma unroll
        for (int rr = 0; rr < 4; rr++) av[rr] = __shfl(alpha, quad * 4 + rr, 64);
#pragma unroll
        for (int dt = 0; dt < 4; dt++)
#pragma unroll
            for (int rr = 0; rr < 4; rr++) o[dt][rr] *= av[rr];

        // G: write P to LDS (wave-private rows; same-wave DS ordering suffices)
#pragma unroll
        for (int t = 0; t < 4; t++) {
            unsigned p01 = (unsigned)f2bf(sacc[t][0]) | ((unsigned)f2bf(sacc[t][1]) << 16);
            unsigned p23 = (unsigned)f2bf(sacc[t][2]) | ((unsigned)f2bf(sacc[t][3]) << 16);
            uint2 pw; pw.x = p01; pw.y = p23;
            *(uint2*)(&Ps[(wave * 16 + l) * 72 + t * 16 + quad * 4]) = pw;
        }

        // H: PV: O += P * V
        bf16x8 pa0 = *(const bf16x8*)(&Ps[(wave * 16 + l) * 72 + quad * 8]);
        bf16x8 pa1 = *(const bf16x8*)(&Ps[(wave * 16 + l) * 72 + 32 + quad * 8]);
#pragma unroll
        for (int dt = 0; dt < 4; dt++) {
            bf16x8 v0 = *(const bf16x8*)(&Vts[(dt * 16 + l) * 72 + quad * 8]);
            o[dt] = __builtin_amdgcn_mfma_f32_16x16x32_bf16(pa0, v0, o[dt], 0, 0, 0);
            bf16x8 v1 = *(const bf16x8*)(&Vts[(dt * 16 + l) * 72 + 32 + quad * 8]);
            o[dt] = __builtin_amdgcn_mfma_f32_16x16x32_bf16(pa1, v1, o[dt], 0, 0, 0);
        }
        LDS_BARRIER();
    }

    // epilogue: unnormalized partial O + per-row (m, l) for this split
    float* Op = Opart + (((size_t)split * B_ * NH_ + bh) * S_ + q0) * HD_;
#pragma unroll
    for (int dt = 0; dt < 4; dt++) {
#pragma unroll
        for (int rr = 0; rr < 4; rr++) {
            const int row = wave * 16 + quad * 4 + rr;
            Op[(size_t)row * HD_ + dt * 16 + l] = o[dt][rr];
        }
    }
    if (quad == 0) {
        const size_t mi = ((size_t)split * B_ * NH_ + bh) * S_ + q0 + wave * 16 + l;
        Mpart[mi] = m_run;
        Lpart[mi] = l_run;
    }
}

// ---------------- split-K combine ----------------
// One thread per (row, 4 d-elems). Standard flash merge in f32:
//   m = max(m0,m1); out = (O0*e^{m0-m} + O1*e^{m1-m}) / (l0*e^{m0-m} + l1*e^{m1-m})
__global__ __launch_bounds__(256) void combine(
    const float* __restrict__ Op, const float* __restrict__ Mp, const float* __restrict__ Lp,
    float* __restrict__ out)
{
    const int idx = blockIdx.x * 256 + threadIdx.x;   // NROWS*16 total
    const int r = idx >> 4;            // bh*S + s
    const int dseg = (idx & 15) * 4;
    const float m0 = Mp[r], m1 = Mp[NROWS + r];
    const float l0 = Lp[r], l1 = Lp[NROWS + r];
    const float m = fmaxf(m0, m1);
    const float a0 = __expf(m0 - m), a1 = __expf(m1 - m);
    const float inv = 1.0f / (l0 * a0 + l1 * a1);
    const float4 o0 = *(const float4*)(Op + (size_t)r * HD_ + dseg);
    const float4 o1 = *(const float4*)(Op + ((size_t)NROWS + r) * HD_ + dseg);
    float4 res;
    res.x = (o0.x * a0 + o1.x * a1) * inv;
    res.y = (o0.y * a0 + o1.y * a1) * inv;
    res.z = (o0.z * a0 + o1.z * a1) * inv;
    res.w = (o0.w * a0 + o1.w * a1) * inv;
    const int bh_ = r >> 11;                // r / S_
    const int s = r & (S_ - 1);
    const int b = bh_ / NH_;
    const int h = bh_ - b * NH_;
    *(float4*)(out + ((size_t)(b * S_ + s)) * HID_ + h * HD_ + dseg) = res;
}

extern "C" void kernel_launch(void* const* d_in, const int* in_sizes, int n_in,
                              void* d_out, int out_size, void* d_ws, size_t ws_size,
                              hipStream_t stream) {
    const float* hs   = (const float*)d_in[0];
    const float* rel  = (const float*)d_in[1];
    const float* rel2 = (const float*)d_in[2];
    const int*   mask = (const int*)d_in[3];
    const float* Wq = (const float*)d_in[4];
    const float* bq = (const float*)d_in[5];
    const float* Wk = (const float*)d_in[6];
    const float* bk = (const float*)d_in[7];
    const float* Wv = (const float*)d_in[8];
    const float* bv = (const float*)d_in[9];
    float* out = (float*)d_out;

    char* ws = (char*)d_ws;
    u16* hsb   = (u16*)(ws);                      // 4096*768 bf16   = 6291456 B
    u16* wcat  = (u16*)(ws + 6291456);            // 2304*768 bf16   = 3538944 B
    u16* Qg    = (u16*)(ws + 9830400);            // [B][NH][S][HD]  = 6291456 B
    u16* Kg    = (u16*)(ws + 16121856);           // same
    u16* Vtg   = (u16*)(ws + 22413312);           // [B][NH][HD][S]  = 6291456 B
    float* Opart = (float*)(ws + 28704768);       // [2][B][NH][S][HD] f32 = 25165824 B
    float* Mpart = (float*)(ws + 53870592);       // [2][B*NH*S] f32 = 393216 B
    float* Lpart = (float*)(ws + 54263808);       // [2][B*NH*S] f32 = 393216 B

    // casts
    cast_bf16<<<3072, 256, 0, stream>>>(hs, hsb, B_ * S_ * HID_);
    cast_bf16<<<576, 256, 0, stream>>>(Wq, wcat,             HID_ * HID_);
    cast_bf16<<<576, 256, 0, stream>>>(Wk, wcat + HID_ * HID_,     HID_ * HID_);
    cast_bf16<<<576, 256, 0, stream>>>(Wv, wcat + 2 * HID_ * HID_, HID_ * HID_);

    // QKV projections
    qkv_gemm<<<dim3(64, 36), 256, 0, stream>>>(hsb, wcat, bq, bk, bv, Qg, Kg, Vtg);

    // fused attention, 2-way split-K
    attn<<<dim3(S_ / 64, NH_, B_ * NSPLIT), 256, 0, stream>>>(
        Qg, Kg, Vtg, rel, rel2, mask, Opart, Mpart, Lpart);

    // merge halves
    combine<<<(NROWS * 16) / 256, 256, 0, stream>>>(Opart, Mpart, Lpart, out);
}

// Round 6
// 880.241 us; speedup vs baseline: 1.9291x; 1.0289x over previous
//
#include <hip/hip_runtime.h>

#define B_ 2
#define S_ 2048
#define HID_ 768
#define NH_ 12
#define HD_ 64
#define NSPLIT 2
#define KSPAN (S_ / NSPLIT)
#define NROWS (B_ * NH_ * S_)   // 49152 total (bh, s) rows

typedef unsigned short u16;
typedef __attribute__((ext_vector_type(8))) short bf16x8;
typedef __attribute__((ext_vector_type(4))) float f32x4;

static __device__ inline u16 f2bf(float f) {
    union { float f; unsigned u; } v; v.f = f;
    unsigned r = v.u + 0x7fffu + ((v.u >> 16) & 1u);
    return (u16)(r >> 16);
}

// LDS-only barrier: waits ds ops, leaves vmcnt (global loads) IN FLIGHT.
#define LDS_BARRIER() asm volatile("s_waitcnt lgkmcnt(0)\n\ts_barrier" ::: "memory")

// ---------------- cast fp32 -> bf16, 4 elems/thread ----------------
__global__ void cast_bf16(const float* __restrict__ src, u16* __restrict__ dst, int n) {
    int i = (blockIdx.x * blockDim.x + threadIdx.x) * 4;
    if (i < n) {
        float4 v = *(const float4*)(src + i);
        unsigned lo = (unsigned)f2bf(v.x) | ((unsigned)f2bf(v.y) << 16);
        unsigned hi = (unsigned)f2bf(v.z) | ((unsigned)f2bf(v.w) << 16);
        uint2 o; o.x = lo; o.y = hi;
        *(uint2*)(dst + i) = o;
    }
}

// ---------------- QKV projection GEMM ----------------
__global__ __launch_bounds__(256) void qkv_gemm(
    const u16* __restrict__ hsb, const u16* __restrict__ wcat,
    const float* __restrict__ bq, const float* __restrict__ bk, const float* __restrict__ bv,
    u16* __restrict__ Qg, u16* __restrict__ Kg, u16* __restrict__ Vtg)
{
    __shared__ u16 As[64 * 40];
    __shared__ u16 Bs[64 * 40];
    __shared__ u16 Vs[64 * 72];

    const int m0 = blockIdx.x * 64;
    const int n0 = blockIdx.y * 64;
    const int tid = threadIdx.x;
    const int wave = tid >> 6, lane = tid & 63;
    const int l = lane & 15, quad = lane >> 4;

    f32x4 acc[4];
#pragma unroll
    for (int t = 0; t < 4; t++) acc[t] = (f32x4){0.f, 0.f, 0.f, 0.f};

    const int srow = tid >> 2;          // 0..63
    const int skg = (tid & 3) * 8;      // 0,8,16,24

    for (int k0 = 0; k0 < HID_; k0 += 32) {
        *(int4*)(&As[srow * 40 + skg]) = *(const int4*)(&hsb[(size_t)(m0 + srow) * HID_ + k0 + skg]);
        *(int4*)(&Bs[srow * 40 + skg]) = *(const int4*)(&wcat[(size_t)(n0 + srow) * HID_ + k0 + skg]);
        __syncthreads();
        bf16x8 a = *(const bf16x8*)(&As[(wave * 16 + l) * 40 + quad * 8]);
#pragma unroll
        for (int t = 0; t < 4; t++) {
            bf16x8 b = *(const bf16x8*)(&Bs[(t * 16 + l) * 40 + quad * 8]);
            acc[t] = __builtin_amdgcn_mfma_f32_16x16x32_bf16(a, b, acc[t], 0, 0, 0);
        }
        __syncthreads();
    }

    const int proj = n0 / HID_;             // 0=Q 1=K 2=V
    const int cbase = n0 - proj * HID_;     // multiple of 64
    const int h = cbase >> 6;
    const int bidx = m0 >> 11;
    const int srow0 = m0 & (S_ - 1);
    const float* bias = (proj == 0) ? bq : ((proj == 1) ? bk : bv);

    if (proj < 2) {
        u16* dst = (proj == 0) ? Qg : Kg;
        const float sc = (proj == 0) ? 0.125f : 1.0f;
#pragma unroll
        for (int t = 0; t < 4; t++) {
            const int d = t * 16 + l;
            const float bb = bias[cbase + d];
#pragma unroll
            for (int rr = 0; rr < 4; rr++) {
                int s = srow0 + wave * 16 + quad * 4 + rr;
                float v = (acc[t][rr] + bb) * sc;
                dst[(((size_t)bidx * NH_ + h) * S_ + s) * HD_ + d] = f2bf(v);
            }
        }
    } else {
        // V: transpose through LDS, write Vt[b][h][d][s] coalesced
#pragma unroll
        for (int t = 0; t < 4; t++) {
            const int d = t * 16 + l;
            const float bb = bias[cbase + d];
#pragma unroll
            for (int rr = 0; rr < 4; rr++) {
                int sl = wave * 16 + quad * 4 + rr;
                Vs[d * 72 + sl] = f2bf(acc[t][rr] + bb);
            }
        }
        __syncthreads();
        const int drow = tid >> 2;           // d 0..63
        const int sseg = (tid & 3) * 16;     // s segment
        size_t base = (((size_t)bidx * NH_ + h) * HD_ + drow) * S_ + srow0 + sseg;
        *(int4*)(&Vtg[base])     = *(const int4*)(&Vs[drow * 72 + sseg]);
        *(int4*)(&Vtg[base + 8]) = *(const int4*)(&Vs[drow * 72 + sseg + 8]);
    }
}

// ---------------- fused flash attention, 2-way split-K, coalesced rel stream ----
// grid: (S/64, NH, B*NSPLIT), 256 threads = 4 waves.
// rel/rel2/mask are loaded with a COALESCED wave-local assignment: lane i owns
// row wave*16+(i>>2), cols 4*(i&3)+16t -> lanes 0-3 read 64 B contiguous (the
// old mapping put consecutive lanes 8 KB apart -> ~4x request amplification).
// The masked sum ss[t] is then redistributed to the MFMA sacc layout by ONE
// fixed lane permutation: consumer lane (l,quad) reads stager lane 4l+quad
// (bijective; stager lane 4l+q holds row l, cols 4q+16t -> exactly consumer
// (l,q)'s fragment t). 16 __shfl, zero LDS growth, zero cross-iteration regs.
__global__ __launch_bounds__(256) void attn(
    const u16* __restrict__ Qg, const u16* __restrict__ Kg, const u16* __restrict__ Vtg,
    const float* __restrict__ rel, const float* __restrict__ rel2,
    const int* __restrict__ mask,
    float* __restrict__ Opart, float* __restrict__ Mpart, float* __restrict__ Lpart)
{
    __shared__ u16 Ks[64 * 72];
    __shared__ u16 Vts[64 * 72];
    __shared__ u16 Ps[4 * 16 * 72];

    const int q0 = blockIdx.x * 64;
    const int h = blockIdx.y;
    const int b = blockIdx.z / NSPLIT;
    const int split = blockIdx.z - b * NSPLIT;
    const int tid = threadIdx.x;
    const int wave = tid >> 6, lane = tid & 63;
    const int l = lane & 15, quad = lane >> 4;
    const int bh = b * NH_ + h;
    const int kbase = split * KSPAN;
    const int kend = kbase + KSPAN;

    const float NEG = -3.4028234663852886e38f;

    // Q fragments (B-operand of swapped MFMA) stay in registers
    bf16x8 qf[2];
    {
        const int qr = q0 + wave * 16 + l;
        qf[0] = *(const bf16x8*)(&Qg[((size_t)bh * S_ + qr) * HD_ + quad * 8]);
        qf[1] = *(const bf16x8*)(&Qg[((size_t)bh * S_ + qr) * HD_ + 32 + quad * 8]);
    }

    f32x4 o[4];
#pragma unroll
    for (int t = 0; t < 4; t++) o[t] = (f32x4){0.f, 0.f, 0.f, 0.f};
    float m_run = NEG, l_run = 0.f;   // lane reduces q-row q0+wave*16+l

    const int srow = tid >> 2;        // K/V staging row 0..63 (block-wide)
    const int sseg = (tid & 3) * 8;   // 0,8,16,24

    // rel/rel2/mask staging: wave-local coalesced mapping
    const int rsub = lane >> 2;             // row-within-wave 0..15
    const int rcol = (lane & 3) * 4;        // float col base within each 16-block
    const int rrow = q0 + wave * 16 + rsub; // absolute q-row this lane stages
    const float* relS  = rel  + (size_t)bh * S_ * S_ + (size_t)rrow * S_;
    const float* rel2S = rel2 + (size_t)bh * S_ * S_ + (size_t)rrow * S_;
    const int*   maskS = mask + (size_t)b  * S_ * S_ + (size_t)rrow * S_;
    const int srcLane = 4 * l + quad;       // redistribution permutation

    for (int k0 = kbase; k0 < kend; k0 += 64) {
        // A: issue all global loads, coalesced. K/V first (oldest in queue),
        // then rel/rel2/mask interleaved in triples so counted vmcnt lets the
        // masked-sum consume them oldest-first while the rest stay in flight.
        size_t kg = ((size_t)bh * S_ + k0 + srow) * HD_;
        int4 ka = *(const int4*)(&Kg[kg + sseg]);
        int4 kb = *(const int4*)(&Kg[kg + 32 + sseg]);
        size_t vg = ((size_t)bh * HD_ + srow) * S_ + k0;
        int4 va = *(const int4*)(&Vtg[vg + sseg]);
        int4 vb = *(const int4*)(&Vtg[vg + 32 + sseg]);

        float4 r[4], s2[4];
        int4 mk[4];
#pragma unroll
        for (int i = 0; i < 4; i++) {
            const int c = k0 + rcol + i * 16;
            r[i]  = *(const float4*)(relS + c);
            s2[i] = *(const float4*)(rel2S + c);
            mk[i] = *(const int4*)(maskS + c);
        }

        // B: write staged K/V to LDS (counted vmcnt: waits only ka..vb)
        *(int4*)(&Ks[srow * 72 + sseg])       = ka;
        *(int4*)(&Ks[srow * 72 + 32 + sseg])  = kb;
        *(int4*)(&Vts[srow * 72 + sseg])      = va;
        *(int4*)(&Vts[srow * 72 + 32 + sseg]) = vb;

        // C: masked sums in the stager layout. Mask pre-folded: adding
        // |qk|<=1e4 to -3.4e38 is below the ulp -> bit-identical to post-mask.
        f32x4 ss[4];
#pragma unroll
        for (int i = 0; i < 4; i++) {
            ss[i][0] = mk[i].x ? NEG : r[i].x + s2[i].x;
            ss[i][1] = mk[i].y ? NEG : r[i].y + s2[i].y;
            ss[i][2] = mk[i].z ? NEG : r[i].z + s2[i].z;
            ss[i][3] = mk[i].w ? NEG : r[i].w + s2[i].w;
        }

        // D: redistribute to MFMA layout: sacc[t] = ss[t] of lane 4l+quad
        f32x4 sacc[4];
#pragma unroll
        for (int t = 0; t < 4; t++) {
            sacc[t][0] = __shfl(ss[t][0], srcLane, 64);
            sacc[t][1] = __shfl(ss[t][1], srcLane, 64);
            sacc[t][2] = __shfl(ss[t][2], srcLane, 64);
            sacc[t][3] = __shfl(ss[t][3], srcLane, 64);
        }

        LDS_BARRIER();   // K/V visible to all waves

        // E: swapped QK^T: sacc[t][rr] = scores[qrow][k0 + t*16 + quad*4 + rr]
#pragma unroll
        for (int t = 0; t < 4; t++) {
            bf16x8 b0 = *(const bf16x8*)(&Ks[(t * 16 + l) * 72 + quad * 8]);
            sacc[t] = __builtin_amdgcn_mfma_f32_16x16x32_bf16(b0, qf[0], sacc[t], 0, 0, 0);
            bf16x8 b1 = *(const bf16x8*)(&Ks[(t * 16 + l) * 72 + 32 + quad * 8]);
            sacc[t] = __builtin_amdgcn_mfma_f32_16x16x32_bf16(b1, qf[1], sacc[t], 0, 0, 0);
        }

        // F: online softmax (lanes {l,l+16,l+32,l+48} share a q-row)
        float mx = NEG;
#pragma unroll
        for (int t = 0; t < 4; t++)
#pragma unroll
            for (int rr = 0; rr < 4; rr++) mx = fmaxf(mx, sacc[t][rr]);
        mx = fmaxf(mx, __shfl_xor(mx, 16, 64));
        mx = fmaxf(mx, __shfl_xor(mx, 32, 64));
        float mnew = fmaxf(m_run, mx);
        float alpha = __expf(m_run - mnew);
        float rs = 0.f;
#pragma unroll
        for (int t = 0; t < 4; t++)
#pragma unroll
            for (int rr = 0; rr < 4; rr++) {
                float p = __expf(sacc[t][rr] - mnew);
                sacc[t][rr] = p;
                rs += p;
            }
        rs += __shfl_xor(rs, 16, 64);
        rs += __shfl_xor(rs, 32, 64);
        l_run = l_run * alpha + rs;
        m_run = mnew;

        float av[4];
#pragma unroll
        for (int rr = 0; rr < 4; rr++) av[rr] = __shfl(alpha, quad * 4 + rr, 64);
#pragma unroll
        for (int dt = 0; dt < 4; dt++)
#pragma unroll
            for (int rr = 0; rr < 4; rr++) o[dt][rr] *= av[rr];

        // G: write P to LDS (wave-private rows; same-wave DS ordering suffices)
#pragma unroll
        for (int t = 0; t < 4; t++) {
            unsigned p01 = (unsigned)f2bf(sacc[t][0]) | ((unsigned)f2bf(sacc[t][1]) << 16);
            unsigned p23 = (unsigned)f2bf(sacc[t][2]) | ((unsigned)f2bf(sacc[t][3]) << 16);
            uint2 pw; pw.x = p01; pw.y = p23;
            *(uint2*)(&Ps[(wave * 16 + l) * 72 + t * 16 + quad * 4]) = pw;
        }

        // H: PV: O += P * V
        bf16x8 pa0 = *(const bf16x8*)(&Ps[(wave * 16 + l) * 72 + quad * 8]);
        bf16x8 pa1 = *(const bf16x8*)(&Ps[(wave * 16 + l) * 72 + 32 + quad * 8]);
#pragma unroll
        for (int dt = 0; dt < 4; dt++) {
            bf16x8 v0 = *(const bf16x8*)(&Vts[(dt * 16 + l) * 72 + quad * 8]);
            o[dt] = __builtin_amdgcn_mfma_f32_16x16x32_bf16(pa0, v0, o[dt], 0, 0, 0);
            bf16x8 v1 = *(const bf16x8*)(&Vts[(dt * 16 + l) * 72 + 32 + quad * 8]);
            o[dt] = __builtin_amdgcn_mfma_f32_16x16x32_bf16(pa1, v1, o[dt], 0, 0, 0);
        }
        LDS_BARRIER();   // all waves' LDS reads done before next tile's staging
    }

    // epilogue: unnormalized partial O + per-row (m, l) for this split
    float* Op = Opart + (((size_t)split * B_ * NH_ + bh) * S_ + q0) * HD_;
#pragma unroll
    for (int dt = 0; dt < 4; dt++) {
#pragma unroll
        for (int rr = 0; rr < 4; rr++) {
            const int row = wave * 16 + quad * 4 + rr;
            Op[(size_t)row * HD_ + dt * 16 + l] = o[dt][rr];
        }
    }
    if (quad == 0) {
        const size_t mi = ((size_t)split * B_ * NH_ + bh) * S_ + q0 + wave * 16 + l;
        Mpart[mi] = m_run;
        Lpart[mi] = l_run;
    }
}

// ---------------- split-K combine ----------------
__global__ __launch_bounds__(256) void combine(
    const float* __restrict__ Op, const float* __restrict__ Mp, const float* __restrict__ Lp,
    float* __restrict__ out)
{
    const int idx = blockIdx.x * 256 + threadIdx.x;   // NROWS*16 total
    const int r = idx >> 4;            // bh*S + s
    const int dseg = (idx & 15) * 4;
    const float m0 = Mp[r], m1 = Mp[NROWS + r];
    const float l0 = Lp[r], l1 = Lp[NROWS + r];
    const float m = fmaxf(m0, m1);
    const float a0 = __expf(m0 - m), a1 = __expf(m1 - m);
    const float inv = 1.0f / (l0 * a0 + l1 * a1);
    const float4 o0 = *(const float4*)(Op + (size_t)r * HD_ + dseg);
    const float4 o1 = *(const float4*)(Op + ((size_t)NROWS + r) * HD_ + dseg);
    float4 res;
    res.x = (o0.x * a0 + o1.x * a1) * inv;
    res.y = (o0.y * a0 + o1.y * a1) * inv;
    res.z = (o0.z * a0 + o1.z * a1) * inv;
    res.w = (o0.w * a0 + o1.w * a1) * inv;
    const int bh_ = r >> 11;                // r / S_
    const int s = r & (S_ - 1);
    const int b = bh_ / NH_;
    const int h = bh_ - b * NH_;
    *(float4*)(out + ((size_t)(b * S_ + s)) * HID_ + h * HD_ + dseg) = res;
}

extern "C" void kernel_launch(void* const* d_in, const int* in_sizes, int n_in,
                              void* d_out, int out_size, void* d_ws, size_t ws_size,
                              hipStream_t stream) {
    const float* hs   = (const float*)d_in[0];
    const float* rel  = (const float*)d_in[1];
    const float* rel2 = (const float*)d_in[2];
    const int*   mask = (const int*)d_in[3];
    const float* Wq = (const float*)d_in[4];
    const float* bq = (const float*)d_in[5];
    const float* Wk = (const float*)d_in[6];
    const float* bk = (const float*)d_in[7];
    const float* Wv = (const float*)d_in[8];
    const float* bv = (const float*)d_in[9];
    float* out = (float*)d_out;

    char* ws = (char*)d_ws;
    u16* hsb   = (u16*)(ws);                      // 4096*768 bf16   = 6291456 B
    u16* wcat  = (u16*)(ws + 6291456);            // 2304*768 bf16   = 3538944 B
    u16* Qg    = (u16*)(ws + 9830400);            // [B][NH][S][HD]  = 6291456 B
    u16* Kg    = (u16*)(ws + 16121856);           // same
    u16* Vtg   = (u16*)(ws + 22413312);           // [B][NH][HD][S]  = 6291456 B
    float* Opart = (float*)(ws + 28704768);       // [2][B][NH][S][HD] f32 = 25165824 B
    float* Mpart = (float*)(ws + 53870592);       // [2][B*NH*S] f32 = 393216 B
    float* Lpart = (float*)(ws + 54263808);       // [2][B*NH*S] f32 = 393216 B

    // casts
    cast_bf16<<<3072, 256, 0, stream>>>(hs, hsb, B_ * S_ * HID_);
    cast_bf16<<<576, 256, 0, stream>>>(Wq, wcat,             HID_ * HID_);
    cast_bf16<<<576, 256, 0, stream>>>(Wk, wcat + HID_ * HID_,     HID_ * HID_);
    cast_bf16<<<576, 256, 0, stream>>>(Wv, wcat + 2 * HID_ * HID_, HID_ * HID_);

    // QKV projections
    qkv_gemm<<<dim3(64, 36), 256, 0, stream>>>(hsb, wcat, bq, bk, bv, Qg, Kg, Vtg);

    // fused attention, 2-way split-K
    attn<<<dim3(S_ / 64, NH_, B_ * NSPLIT), 256, 0, stream>>>(
        Qg, Kg, Vtg, rel, rel2, mask, Opart, Mpart, Lpart);

    // merge halves
    combine<<<(NROWS * 16) / 256, 256, 0, stream>>>(Opart, Mpart, Lpart, out);
}